// Round 6
// baseline (815.550 us; speedup 1.0000x reference)
//
#include <hip/hip_runtime.h>
#include <hip/hip_bf16.h>

#define N_NODES 50000
#define IN_C    96
#define HID_C   128
#define OUT_C   64
#define MROWS   50048 // 64-row-tile padded M

// Bucket partition: 1000 buckets x 50 nodes. Edge-parallel gathers consume
// the packed pairs directly -- no CSR, no adj, no rank pass.
#define NB      1000  // buckets
#define BSZ     50    // nodes per bucket (1000*50 = 50000)
#define WCHUNK  4096  // edges per workgroup in scatter (R4-proven)
#define NWG     196   // ceil(800000/4096)
#define BCAP    2048  // per-bucket capacity (mean 800, sd 28 -> +44 sigma)

// conv fusion split (conv blocks appended after scatter blocks)
#define XBLKS   2344  // ceil(50000*12/256)
#define WBLKS   160   // (128*192 + 128*128)/256

typedef __attribute__((ext_vector_type(8))) short short8;  // 8 bf16 (4 VGPR)
typedef __attribute__((ext_vector_type(4))) float f32x4;

// round-to-nearest-even fp32 -> bf16 bits
__device__ inline unsigned int f2bf(float f) {
    unsigned int u = __float_as_uint(f);
    return (u + 0x7fffu + ((u >> 16) & 1u)) >> 16;
}
__device__ inline unsigned int pack2(float lo, float hi) {
    return f2bf(lo) | (f2bf(hi) << 16);
}
__device__ inline float blo(unsigned int u) { return __uint_as_float(u << 16); }
__device__ inline float bhi(unsigned int u) { return __uint_as_float(u & 0xffff0000u); }

// ---------------------------------------------------------------------------
// Fused scatter+conv: blocks [0,NWG) bucket-partition edges into packed u32
// (localdst<<17 | src) via LDS hist + one global atomicAdd reservation per
// (WG,bucket); blocks [NWG,NWG+XBLKS) convert x fp32->bf16; rest W1t/W2t.
// gcnt zeroed by hipMemsetAsync on the same stream.
// ---------------------------------------------------------------------------
__global__ __launch_bounds__(256) void scatter_conv_kernel(
    const int* __restrict__ src, const int* __restrict__ dst,
    int* __restrict__ gcnt, unsigned int* __restrict__ pairs, int E,
    const float* __restrict__ x, uint4* __restrict__ xb4,
    const float* __restrict__ w1l, const float* __restrict__ w1r,
    const float* __restrict__ w2l, const float* __restrict__ w2r,
    unsigned short* __restrict__ wt1, unsigned short* __restrict__ wt2)
{
    __shared__ int lsrc[WCHUNK];
    __shared__ int ldst[WCHUNK];
    __shared__ int h[NB];      // hist, then reused as cur
    __shared__ int wbase[NB];  // this WG's reserved base per bucket
    int blk = blockIdx.x;
    int t = threadIdx.x;
    if (blk < NWG) {
        int base_e = blk * WCHUNK;
        int rem = E - base_e; if (rem > WCHUNK) rem = WCHUNK;
        {
            const int4* s4 = (const int4*)(src + base_e);
            const int4* d4 = (const int4*)(dst + base_e);
            int nv = rem >> 2;
            for (int k = t; k < nv; k += 256) {
                ((int4*)lsrc)[k] = s4[k];
                ((int4*)ldst)[k] = d4[k];
            }
            for (int i = (nv << 2) + t; i < rem; i += 256) {
                lsrc[i] = src[base_e + i];
                ldst[i] = dst[base_e + i];
            }
        }
        for (int i = t; i < NB; i += 256) h[i] = 0;
        __syncthreads();
        for (int i = t; i < rem; i += 256)
            atomicAdd(&h[ldst[i] / BSZ], 1);
        __syncthreads();
        for (int i = t; i < NB; i += 256) {
            wbase[i] = atomicAdd(&gcnt[i], h[i]);
            h[i] = 0;                              // becomes cur
        }
        __syncthreads();
        for (int i = t; i < rem; i += 256) {
            int d = ldst[i];
            int b = d / BSZ;
            int r = atomicAdd(&h[b], 1);
            int pos = wbase[b] + r;
            if (pos < BCAP)                        // stat-impossible overflow guard
                pairs[(size_t)b * BCAP + pos] =
                    ((unsigned)(d - b * BSZ) << 17) | (unsigned)lsrc[i];
        }
        return;
    }
    blk -= NWG;
    if (blk < XBLKS) {
        int idx = blk * 256 + t;
        if (idx >= N_NODES * 12) return;
        const float4* x4 = (const float4*)x;
        float4 u = x4[(size_t)idx * 2];
        float4 v = x4[(size_t)idx * 2 + 1];
        uint4 w;
        w.x = pack2(u.x, u.y); w.y = pack2(u.z, u.w);
        w.z = pack2(v.x, v.y); w.w = pack2(v.z, v.w);
        xb4[idx] = w;
    } else {
        int i = (blk - XBLKS) * 256 + t;
        if (i < 128 * 192) {
            int col = i / 192, k = i - col * 192;
            float v = (k < 96) ? w1l[k * 128 + col] : w1r[(k - 96) * 128 + col];
            wt1[i] = (unsigned short)f2bf(v);
        } else {
            int j = i - 128 * 192;
            int col = j / 128, k = j - col * 128;
            float v = (col < 64) ? w2l[k * 64 + col] : w2r[k * 64 + col - 64];
            wt2[j] = (unsigned short)f2bf(v);
        }
    }
}

// ---------------------------------------------------------------------------
// Gather 1, edge-parallel: block = bucket. Stage pairs in LDS, hist localdst
// for deg, then items (edge x 12 chunks) do one random 16B load + 8
// ds_add_f32 into acc[localdst][96] (stride 100 floats: rotates banks by 4
// per localdst, breaking the c*8 mod 32 collision pattern). No divergence,
// no adj array. Writeback: agg[n] = acc/deg as bf16.
// ---------------------------------------------------------------------------
#define G1S 100   // acc row stride (floats)
__global__ __launch_bounds__(256) void gather1_ep(
    const unsigned int* __restrict__ pairs, const int* __restrict__ gcnt,
    const uint4* __restrict__ xb4, uint4* __restrict__ agg4)
{
    __shared__ __align__(16) unsigned int lp[BCAP];  // 8 KB
    __shared__ float acc[BSZ * G1S];                 // 20 KB
    __shared__ int hist[BSZ];
    int b = blockIdx.x;
    int t = threadIdx.x;
    int n = gcnt[b]; if (n > BCAP) n = BCAP;
    int node0 = b * BSZ;
    for (int i = t; i < BSZ * G1S; i += 256) acc[i] = 0.f;
    if (t < BSZ) hist[t] = 0;
    {
        const uint4* p4 = (const uint4*)(pairs + (size_t)b * BCAP);
        int nv = (n + 3) >> 2;
        for (int k = t; k < nv; k += 256) ((uint4*)lp)[k] = p4[k];
    }
    __syncthreads();
    for (int i = t; i < n; i += 256) atomicAdd(&hist[lp[i] >> 17], 1);
    int total = n * 12;
    int i = t;
    for (; i + 768 < total; i += 1024) {
        int i0 = i, i1 = i + 256, i2 = i + 512, i3 = i + 768;
        int e0 = i0 / 12, c0 = i0 - e0 * 12;
        int e1 = i1 / 12, c1 = i1 - e1 * 12;
        int e2 = i2 / 12, c2 = i2 - e2 * 12;
        int e3 = i3 / 12, c3 = i3 - e3 * 12;
        unsigned p0 = lp[e0], p1 = lp[e1], p2 = lp[e2], p3 = lp[e3];
        uint4 u0 = xb4[(size_t)(p0 & 0x1FFFFu) * 12 + c0];
        uint4 u1 = xb4[(size_t)(p1 & 0x1FFFFu) * 12 + c1];
        uint4 u2 = xb4[(size_t)(p2 & 0x1FFFFu) * 12 + c2];
        uint4 u3 = xb4[(size_t)(p3 & 0x1FFFFu) * 12 + c3];
        float* a0 = &acc[(p0 >> 17) * G1S + c0 * 8];
        float* a1 = &acc[(p1 >> 17) * G1S + c1 * 8];
        float* a2 = &acc[(p2 >> 17) * G1S + c2 * 8];
        float* a3 = &acc[(p3 >> 17) * G1S + c3 * 8];
        atomicAdd(&a0[0], blo(u0.x)); atomicAdd(&a0[1], bhi(u0.x));
        atomicAdd(&a0[2], blo(u0.y)); atomicAdd(&a0[3], bhi(u0.y));
        atomicAdd(&a0[4], blo(u0.z)); atomicAdd(&a0[5], bhi(u0.z));
        atomicAdd(&a0[6], blo(u0.w)); atomicAdd(&a0[7], bhi(u0.w));
        atomicAdd(&a1[0], blo(u1.x)); atomicAdd(&a1[1], bhi(u1.x));
        atomicAdd(&a1[2], blo(u1.y)); atomicAdd(&a1[3], bhi(u1.y));
        atomicAdd(&a1[4], blo(u1.z)); atomicAdd(&a1[5], bhi(u1.z));
        atomicAdd(&a1[6], blo(u1.w)); atomicAdd(&a1[7], bhi(u1.w));
        atomicAdd(&a2[0], blo(u2.x)); atomicAdd(&a2[1], bhi(u2.x));
        atomicAdd(&a2[2], blo(u2.y)); atomicAdd(&a2[3], bhi(u2.y));
        atomicAdd(&a2[4], blo(u2.z)); atomicAdd(&a2[5], bhi(u2.z));
        atomicAdd(&a2[6], blo(u2.w)); atomicAdd(&a2[7], bhi(u2.w));
        atomicAdd(&a3[0], blo(u3.x)); atomicAdd(&a3[1], bhi(u3.x));
        atomicAdd(&a3[2], blo(u3.y)); atomicAdd(&a3[3], bhi(u3.y));
        atomicAdd(&a3[4], blo(u3.z)); atomicAdd(&a3[5], bhi(u3.z));
        atomicAdd(&a3[6], blo(u3.w)); atomicAdd(&a3[7], bhi(u3.w));
    }
    for (; i < total; i += 256) {
        int e = i / 12, c = i - e * 12;
        unsigned pr = lp[e];
        uint4 u = xb4[(size_t)(pr & 0x1FFFFu) * 12 + c];
        float* a = &acc[(pr >> 17) * G1S + c * 8];
        atomicAdd(&a[0], blo(u.x)); atomicAdd(&a[1], bhi(u.x));
        atomicAdd(&a[2], blo(u.y)); atomicAdd(&a[3], bhi(u.y));
        atomicAdd(&a[4], blo(u.z)); atomicAdd(&a[5], bhi(u.z));
        atomicAdd(&a[6], blo(u.w)); atomicAdd(&a[7], bhi(u.w));
    }
    __syncthreads();
    for (int q = t; q < BSZ * 12; q += 256) {
        int ln = q / 12, c = q - ln * 12;
        float id = 1.0f / (float)max(hist[ln], 1);
        const float* ap = &acc[ln * G1S + c * 8];
        uint4 w;
        w.x = pack2(ap[0] * id, ap[1] * id);
        w.y = pack2(ap[2] * id, ap[3] * id);
        w.z = pack2(ap[4] * id, ap[5] * id);
        w.w = pack2(ap[6] * id, ap[7] * id);
        agg4[(size_t)(node0 + ln) * 12 + c] = w;
    }
}

// ---------------------------------------------------------------------------
// Fused GEMM1+GEMM2 (bf16 MFMA), 64-row tiles (unchanged, R4-proven):
//   h  = relu([agg|x] @ W1t^T + b1)  in LDS; [p|q] = h @ W2t^T.
// ---------------------------------------------------------------------------
__global__ __launch_bounds__(256) void gemm12_fused(
    const uint4* __restrict__ agg4, const uint4* __restrict__ xb4,
    const uint4* __restrict__ w1t4, const uint4* __restrict__ w2t4,
    const float* __restrict__ b1, const float* __restrict__ b2,
    unsigned short* __restrict__ p, float* __restrict__ out)
{
    constexpr int KP = 200;   // stage-1 stride in shorts (192+8 pad)
    constexpr int KQ = 136;   // stage-2 stride in shorts (128+8 pad)
    __shared__ unsigned short lw[128 * KP];   // 51200 B
    __shared__ unsigned short la[64 * KP];    // 25600 B
    int t = threadIdx.x;
    uint4* lw4 = (uint4*)lw;
    uint4* la4 = (uint4*)la;

    for (int i = t; i < 128 * 24; i += 256) {
        int r = i / 24, c = i - r * 24;
        lw4[r * 25 + c] = w1t4[i];
    }
    int row0 = blockIdx.x * 64;
    for (int i = t; i < 64 * 24; i += 256) {
        int r = i / 24, c = i - r * 24;
        la4[r * 25 + c] = (c < 12)
            ? agg4[(size_t)(row0 + r) * 12 + c]
            : xb4[(size_t)(row0 + r) * 12 + (c - 12)];
    }
    __syncthreads();

    int wave = t >> 6, lane = t & 63;
    int m = lane & 15, half = lane >> 4;
    int koff = half * 8;
    f32x4 acc[4][2] = {};
#pragma unroll
    for (int k0 = 0; k0 < 192; k0 += 32) {
        short8 B0 = *(const short8*)&lw[(wave * 32 + m)      * KP + k0 + koff];
        short8 B1 = *(const short8*)&lw[(wave * 32 + 16 + m) * KP + k0 + koff];
#pragma unroll
        for (int g = 0; g < 4; g++) {
            short8 A = *(const short8*)&la[(g * 16 + m) * KP + k0 + koff];
            acc[g][0] = __builtin_amdgcn_mfma_f32_16x16x32_bf16(A, B0, acc[g][0], 0, 0, 0);
            acc[g][1] = __builtin_amdgcn_mfma_f32_16x16x32_bf16(A, B1, acc[g][1], 0, 0, 0);
        }
    }
    __syncthreads();

    int col0 = wave * 32 + m, col1 = col0 + 16;
    {
        float bias0 = b1[col0], bias1 = b1[col1];
#pragma unroll
        for (int g = 0; g < 4; g++) {
#pragma unroll
            for (int reg = 0; reg < 4; reg++) {
                int hr = g * 16 + half * 4 + reg;
                la[hr * KQ + col0] = (unsigned short)f2bf(fmaxf(acc[g][0][reg] + bias0, 0.f));
                la[hr * KQ + col1] = (unsigned short)f2bf(fmaxf(acc[g][1][reg] + bias1, 0.f));
            }
        }
    }
    for (int i = t; i < 128 * 16; i += 256) {
        int r = i >> 4, c = i & 15;
        lw4[r * 17 + c] = w2t4[i];
    }
    __syncthreads();

    f32x4 acc2[4][2] = {};
#pragma unroll
    for (int k0 = 0; k0 < 128; k0 += 32) {
        short8 B0 = *(const short8*)&lw[(wave * 32 + m)      * KQ + k0 + koff];
        short8 B1 = *(const short8*)&lw[(wave * 32 + 16 + m) * KQ + k0 + koff];
#pragma unroll
        for (int g = 0; g < 4; g++) {
            short8 A = *(const short8*)&la[(g * 16 + m) * KQ + k0 + koff];
            acc2[g][0] = __builtin_amdgcn_mfma_f32_16x16x32_bf16(A, B0, acc2[g][0], 0, 0, 0);
            acc2[g][1] = __builtin_amdgcn_mfma_f32_16x16x32_bf16(A, B1, acc2[g][1], 0, 0, 0);
        }
    }
#pragma unroll
    for (int g = 0; g < 4; g++) {
#pragma unroll
        for (int reg = 0; reg < 4; reg++) {
            int r = row0 + g * 16 + half * 4 + reg;
            if (r >= N_NODES) continue;
            float v0 = acc2[g][0][reg], v1 = acc2[g][1][reg];
            if (col0 < 64) p[(size_t)r * 64 + col0] = (unsigned short)f2bf(v0);
            else           out[(size_t)r * 64 + col0 - 64] = v0 + b2[col0 - 64];
            if (col1 < 64) p[(size_t)r * 64 + col1] = (unsigned short)f2bf(v1);
            else           out[(size_t)r * 64 + col1 - 64] = v1 + b2[col1 - 64];
        }
    }
}

// ---------------------------------------------------------------------------
// Gather 2, edge-parallel: same scheme over p (64 bf16 = 8 chunks);
// out[n] += acc/deg. acc stride 68 floats (bank rotation by 4).
// ---------------------------------------------------------------------------
#define G2S 68
__global__ __launch_bounds__(256) void gather2_ep(
    const unsigned int* __restrict__ pairs, const int* __restrict__ gcnt,
    const uint4* __restrict__ p4, float* __restrict__ out)
{
    __shared__ __align__(16) unsigned int lp[BCAP];  // 8 KB
    __shared__ float acc[BSZ * G2S];                 // 13.6 KB
    __shared__ int hist[BSZ];
    int b = blockIdx.x;
    int t = threadIdx.x;
    int n = gcnt[b]; if (n > BCAP) n = BCAP;
    int node0 = b * BSZ;
    for (int i = t; i < BSZ * G2S; i += 256) acc[i] = 0.f;
    if (t < BSZ) hist[t] = 0;
    {
        const uint4* pp4 = (const uint4*)(pairs + (size_t)b * BCAP);
        int nv = (n + 3) >> 2;
        for (int k = t; k < nv; k += 256) ((uint4*)lp)[k] = pp4[k];
    }
    __syncthreads();
    for (int i = t; i < n; i += 256) atomicAdd(&hist[lp[i] >> 17], 1);
    int total = n * 8;
    int i = t;
    for (; i + 768 < total; i += 1024) {
        int i0 = i, i1 = i + 256, i2 = i + 512, i3 = i + 768;
        int e0 = i0 >> 3, c0 = i0 & 7;
        int e1 = i1 >> 3, c1 = i1 & 7;
        int e2 = i2 >> 3, c2 = i2 & 7;
        int e3 = i3 >> 3, c3 = i3 & 7;
        unsigned q0 = lp[e0], q1 = lp[e1], q2 = lp[e2], q3 = lp[e3];
        uint4 u0 = p4[(size_t)(q0 & 0x1FFFFu) * 8 + c0];
        uint4 u1 = p4[(size_t)(q1 & 0x1FFFFu) * 8 + c1];
        uint4 u2 = p4[(size_t)(q2 & 0x1FFFFu) * 8 + c2];
        uint4 u3 = p4[(size_t)(q3 & 0x1FFFFu) * 8 + c3];
        float* a0 = &acc[(q0 >> 17) * G2S + c0 * 8];
        float* a1 = &acc[(q1 >> 17) * G2S + c1 * 8];
        float* a2 = &acc[(q2 >> 17) * G2S + c2 * 8];
        float* a3 = &acc[(q3 >> 17) * G2S + c3 * 8];
        atomicAdd(&a0[0], blo(u0.x)); atomicAdd(&a0[1], bhi(u0.x));
        atomicAdd(&a0[2], blo(u0.y)); atomicAdd(&a0[3], bhi(u0.y));
        atomicAdd(&a0[4], blo(u0.z)); atomicAdd(&a0[5], bhi(u0.z));
        atomicAdd(&a0[6], blo(u0.w)); atomicAdd(&a0[7], bhi(u0.w));
        atomicAdd(&a1[0], blo(u1.x)); atomicAdd(&a1[1], bhi(u1.x));
        atomicAdd(&a1[2], blo(u1.y)); atomicAdd(&a1[3], bhi(u1.y));
        atomicAdd(&a1[4], blo(u1.z)); atomicAdd(&a1[5], bhi(u1.z));
        atomicAdd(&a1[6], blo(u1.w)); atomicAdd(&a1[7], bhi(u1.w));
        atomicAdd(&a2[0], blo(u2.x)); atomicAdd(&a2[1], bhi(u2.x));
        atomicAdd(&a2[2], blo(u2.y)); atomicAdd(&a2[3], bhi(u2.y));
        atomicAdd(&a2[4], blo(u2.z)); atomicAdd(&a2[5], bhi(u2.z));
        atomicAdd(&a2[6], blo(u2.w)); atomicAdd(&a2[7], bhi(u2.w));
        atomicAdd(&a3[0], blo(u3.x)); atomicAdd(&a3[1], bhi(u3.x));
        atomicAdd(&a3[2], blo(u3.y)); atomicAdd(&a3[3], bhi(u3.y));
        atomicAdd(&a3[4], blo(u3.z)); atomicAdd(&a3[5], bhi(u3.z));
        atomicAdd(&a3[6], blo(u3.w)); atomicAdd(&a3[7], bhi(u3.w));
    }
    for (; i < total; i += 256) {
        int e = i >> 3, c = i & 7;
        unsigned q = lp[e];
        uint4 u = p4[(size_t)(q & 0x1FFFFu) * 8 + c];
        float* a = &acc[(q >> 17) * G2S + c * 8];
        atomicAdd(&a[0], blo(u.x)); atomicAdd(&a[1], bhi(u.x));
        atomicAdd(&a[2], blo(u.y)); atomicAdd(&a[3], bhi(u.y));
        atomicAdd(&a[4], blo(u.z)); atomicAdd(&a[5], bhi(u.z));
        atomicAdd(&a[6], blo(u.w)); atomicAdd(&a[7], bhi(u.w));
    }
    __syncthreads();
    for (int q = t; q < BSZ * 8; q += 256) {
        int ln = q >> 3, c = q & 7;
        float id = 1.0f / (float)max(hist[ln], 1);
        const float* ap = &acc[ln * G2S + c * 8];
        float4* o4 = (float4*)out;
        size_t base = (size_t)(node0 + ln) * 16 + 2 * c;
        float4 u = o4[base], v = o4[base + 1];
        u.x = fmaf(ap[0], id, u.x); u.y = fmaf(ap[1], id, u.y);
        u.z = fmaf(ap[2], id, u.z); u.w = fmaf(ap[3], id, u.w);
        v.x = fmaf(ap[4], id, v.x); v.y = fmaf(ap[5], id, v.y);
        v.z = fmaf(ap[6], id, v.z); v.w = fmaf(ap[7], id, v.w);
        o4[base] = u; o4[base + 1] = v;
    }
}

extern "C" void kernel_launch(void* const* d_in, const int* in_sizes, int n_in,
                              void* d_out, int out_size, void* d_ws, size_t ws_size,
                              hipStream_t stream)
{
    const float* x   = (const float*)d_in[0];
    const int*   ei  = (const int*)d_in[1];
    const float* w1l = (const float*)d_in[2];
    const float* w1r = (const float*)d_in[3];
    const float* b1  = (const float*)d_in[4];
    const float* w2l = (const float*)d_in[5];
    const float* w2r = (const float*)d_in[6];
    const float* b2  = (const float*)d_in[7];
    float* out = (float*)d_out;

    int E = in_sizes[1] / 2;                  // edge_index is [2, E]
    const int* src = ei;
    const int* dst = ei + E;

    // Workspace layout (4B units, arrays kept 16B-aligned).
    int* gcnt     = (int*)d_ws;                        // 1024 (NB used)
    unsigned int* pairs = (unsigned int*)(gcnt + 1024);// NB*BCAP u32
    unsigned short* xb  = (unsigned short*)(pairs + (size_t)NB * BCAP); // MROWS*96
    unsigned short* agg = xb + (size_t)MROWS * IN_C;   // MROWS*96 bf16
    unsigned short* p   = agg + (size_t)MROWS * IN_C;  // 50000*64 bf16
    unsigned short* Wt1 = p  + (size_t)N_NODES * 64;   // 128*192 bf16
    unsigned short* Wt2 = Wt1 + 128 * 192;             // 128*128 bf16

    // zero bucket counters (stream-ordered, capture-safe)
    hipMemsetAsync(gcnt, 0, NB * sizeof(int), stream);

    // fused: bucket scatter (blocks 0..NWG) + x->bf16 conv + weight transpose
    scatter_conv_kernel<<<NWG + XBLKS + WBLKS, 256, 0, stream>>>(
        src, dst, gcnt, pairs, E,
        x, (uint4*)xb, w1l, w1r, w2l, w2r, Wt1, Wt2);

    gather1_ep<<<NB, 256, 0, stream>>>(
        pairs, gcnt, (const uint4*)xb, (uint4*)agg);

    gemm12_fused<<<MROWS / 64, 256, 0, stream>>>(
        (const uint4*)agg, (const uint4*)xb, (const uint4*)Wt1, (const uint4*)Wt2,
        b1, b2, p, out);

    gather2_ep<<<NB, 256, 0, stream>>>(
        pairs, gcnt, (const uint4*)p, out);
}

// Round 7
// 163.038 us; speedup vs baseline: 5.0022x; 5.0022x over previous
//
#include <hip/hip_runtime.h>
#include <hip/hip_bf16.h>

#define N_NODES 50000
#define IN_C    96
#define HID_C   128
#define OUT_C   64
#define MROWS   50048 // 64-row-tile padded M

// Single-pass CSR build (R4-proven): each WG reserves per-bucket space via
// global atomicAdd on gcnt[NB]; partb re-ranks within buckets.
#define NB      200   // coarse buckets
#define BSZ     250   // nodes per bucket (200*250 = 50000)
#define WCHUNK  4096  // edges per workgroup (R4-proven occupancy point)
#define NWG     196   // ceil(800000/4096)
#define BCAP    8192  // per-bucket capacity (mean 4000, +66 sigma: safe)

// conv fusion split
#define XBLKS   2344  // ceil(50000*12/256)
#define WBLKS   160   // (128*192 + 128*128)/256

typedef __attribute__((ext_vector_type(8))) short short8;  // 8 bf16 (4 VGPR)
typedef __attribute__((ext_vector_type(4))) float f32x4;

// round-to-nearest-even fp32 -> bf16 bits
__device__ inline unsigned int f2bf(float f) {
    unsigned int u = __float_as_uint(f);
    return (u + 0x7fffu + ((u >> 16) & 1u)) >> 16;
}
__device__ inline unsigned int pack2(float lo, float hi) {
    return f2bf(lo) | (f2bf(hi) << 16);
}
__device__ inline float blo(unsigned int u) { return __uint_as_float(u << 16); }
__device__ inline float bhi(unsigned int u) { return __uint_as_float(u & 0xffff0000u); }

// ---------------------------------------------------------------------------
// Fused converter (runs FIRST): blocks [0,XBLKS) convert x fp32 -> xb bf16;
// blocks [XBLKS,..) build W1t[128][192] / W2t[128][128]. Last block also
// zeroes gcnt (stream order guarantees it lands before csr_scatter).
// ---------------------------------------------------------------------------
__global__ __launch_bounds__(256) void conv_all_kernel(
    const float* __restrict__ x, uint4* __restrict__ xb4,
    const float* __restrict__ w1l, const float* __restrict__ w1r,
    const float* __restrict__ w2l, const float* __restrict__ w2r,
    unsigned short* __restrict__ wt1, unsigned short* __restrict__ wt2,
    int* __restrict__ gcnt)
{
    int blk = blockIdx.x;
    if (blk == gridDim.x - 1 && threadIdx.x < NB) gcnt[threadIdx.x] = 0;
    if (blk < XBLKS) {
        int idx = blk * 256 + threadIdx.x;
        if (idx >= N_NODES * 12) return;
        const float4* x4 = (const float4*)x;
        float4 u = x4[(size_t)idx * 2];
        float4 v = x4[(size_t)idx * 2 + 1];
        uint4 w;
        w.x = pack2(u.x, u.y); w.y = pack2(u.z, u.w);
        w.z = pack2(v.x, v.y); w.w = pack2(v.z, v.w);
        xb4[idx] = w;
    } else {
        int i = (blk - XBLKS) * 256 + threadIdx.x;
        if (i < 128 * 192) {
            int col = i / 192, k = i - col * 192;
            float v = (k < 96) ? w1l[k * 128 + col] : w1r[(k - 96) * 128 + col];
            wt1[i] = (unsigned short)f2bf(v);
        } else {
            int j = i - 128 * 192;
            int col = j / 128, k = j - col * 128;
            float v = (col < 64) ? w2l[k * 64 + col] : w2r[k * 64 + col - 64];
            wt2[j] = (unsigned short)f2bf(v);
        }
    }
}

// ---------------------------------------------------------------------------
// CSR pass 1 (single-pass scatter): stage chunk in LDS (int4 loads), LDS
// 200-bin histogram, reserve space per bucket via global atomicAdd, then
// rank+scatter packed edges (localdst<<17 | src) into bucket regions.
// ---------------------------------------------------------------------------
__global__ __launch_bounds__(256) void csr_scatter(
    const int* __restrict__ src, const int* __restrict__ dst,
    int* __restrict__ gcnt, unsigned int* __restrict__ pairs, int E)
{
    __shared__ int lsrc[WCHUNK];
    __shared__ int ldst[WCHUNK];
    __shared__ int h[NB];      // hist, then reused as cur
    __shared__ int wbase[NB];  // this WG's reserved base per bucket
    int t = threadIdx.x;
    int base_e = blockIdx.x * WCHUNK;
    int rem = E - base_e; if (rem > WCHUNK) rem = WCHUNK;
    {
        const int4* s4 = (const int4*)(src + base_e);
        const int4* d4 = (const int4*)(dst + base_e);
        int nv = rem >> 2;
        for (int k = t; k < nv; k += 256) {
            ((int4*)lsrc)[k] = s4[k];
            ((int4*)ldst)[k] = d4[k];
        }
        for (int i = (nv << 2) + t; i < rem; i += 256) {
            lsrc[i] = src[base_e + i];
            ldst[i] = dst[base_e + i];
        }
    }
    if (t < NB) h[t] = 0;
    __syncthreads();
    for (int i = t; i < rem; i += 256)
        atomicAdd(&h[ldst[i] / BSZ], 1);
    __syncthreads();
    if (t < NB) {
        wbase[t] = atomicAdd(&gcnt[t], h[t]);
        h[t] = 0;                                  // becomes cur
    }
    __syncthreads();
    for (int i = t; i < rem; i += 256) {
        int d = ldst[i];
        int b = d / BSZ;
        int r = atomicAdd(&h[b], 1);
        pairs[b * BCAP + wbase[b] + r] =
            ((unsigned)(d - b * BSZ) << 17) | (unsigned)lsrc[i];
    }
}

// ---------------------------------------------------------------------------
// CSR pass 2: per-bucket fine CSR (bucket b region = [b*BCAP, b*BCAP+gcnt[b])).
// LDS 250-bin histogram + scan + rank; uint4-vectorized 4-wide loops.
// ---------------------------------------------------------------------------
__global__ __launch_bounds__(256) void partb_csr(
    const unsigned int* __restrict__ pairs, const int* __restrict__ gcnt,
    int* __restrict__ rowstart, int* __restrict__ cnt,
    int* __restrict__ adj)
{
    __shared__ int h[256];
    __shared__ int buf[256];
    __shared__ int cur[256];
    int b = blockIdx.x;
    int t = threadIdx.x;
    int beg = b * BCAP;
    int n = gcnt[b];
    int node0 = b * BSZ;
    h[t] = 0;
    __syncthreads();
    const uint4* p4 = (const uint4*)(pairs + beg);
    int nv = n >> 2;
    for (int k = t; k < nv; k += 256) {
        uint4 u = p4[k];
        atomicAdd(&h[u.x >> 17], 1);
        atomicAdd(&h[u.y >> 17], 1);
        atomicAdd(&h[u.z >> 17], 1);
        atomicAdd(&h[u.w >> 17], 1);
    }
    for (int i = (nv << 2) + t; i < n; i += 256)
        atomicAdd(&h[pairs[beg + i] >> 17], 1);
    __syncthreads();
    int c = h[t];
    buf[t] = c;
    __syncthreads();
    for (int off = 1; off < 256; off <<= 1) {       // inclusive scan
        int v = (t >= off) ? buf[t - off] : 0;
        __syncthreads();
        buf[t] += v;
        __syncthreads();
    }
    int excl = buf[t] - c;
    if (t < BSZ) {
        rowstart[node0 + t] = beg + excl;
        cnt[node0 + t] = c;
    }
    cur[t] = beg + excl;
    __syncthreads();
    for (int k = t; k < nv; k += 256) {
        uint4 u = p4[k];
        int p0 = atomicAdd(&cur[u.x >> 17], 1);
        int p1 = atomicAdd(&cur[u.y >> 17], 1);
        int p2 = atomicAdd(&cur[u.z >> 17], 1);
        int p3 = atomicAdd(&cur[u.w >> 17], 1);
        adj[p0] = (int)(u.x & 0x1FFFFu);
        adj[p1] = (int)(u.y & 0x1FFFFu);
        adj[p2] = (int)(u.z & 0x1FFFFu);
        adj[p3] = (int)(u.w & 0x1FFFFu);
    }
    for (int i = (nv << 2) + t; i < n; i += 256) {
        unsigned int u = pairs[beg + i];
        int pos = atomicAdd(&cur[u >> 17], 1);
        adj[pos] = (int)(u & 0x1FFFFu);
    }
}

// ---------------------------------------------------------------------------
// Gather 1: agg[n] = (sum_{j in N(n)} xb[j]) / deg(n), bf16 out [50000][96].
// thread = (node, 16B chunk c in 0..11); 4-edge unroll (R4-proven).
// ---------------------------------------------------------------------------
__global__ __launch_bounds__(256) void gather1_kernel(
    const int* __restrict__ rowstart, const int* __restrict__ cnt,
    const int* __restrict__ adj, const uint4* __restrict__ xb4,
    uint4* __restrict__ agg4)
{
    int idx = blockIdx.x * 256 + threadIdx.x;
    if (idx >= N_NODES * 12) return;
    int node = idx / 12;
    int c = idx - node * 12;
    int beg = rowstart[node];
    int d = cnt[node];
    int end = beg + d;
    float a0=0,a1=0,a2=0,a3=0,a4=0,a5=0,a6=0,a7=0;
    float b0=0,b1=0,b2=0,b3=0,b4=0,b5=0,b6=0,b7=0;
    int j = beg;
    for (; j + 3 < end; j += 4) {
        int s0 = adj[j];
        int s1 = adj[j + 1];
        int s2 = adj[j + 2];
        int s3 = adj[j + 3];
        uint4 u = xb4[(size_t)s0 * 12 + c];
        uint4 v = xb4[(size_t)s1 * 12 + c];
        uint4 w = xb4[(size_t)s2 * 12 + c];
        uint4 z = xb4[(size_t)s3 * 12 + c];
        a0 += blo(u.x); a1 += bhi(u.x); a2 += blo(u.y); a3 += bhi(u.y);
        a4 += blo(u.z); a5 += bhi(u.z); a6 += blo(u.w); a7 += bhi(u.w);
        b0 += blo(v.x); b1 += bhi(v.x); b2 += blo(v.y); b3 += bhi(v.y);
        b4 += blo(v.z); b5 += bhi(v.z); b6 += blo(v.w); b7 += bhi(v.w);
        a0 += blo(w.x); a1 += bhi(w.x); a2 += blo(w.y); a3 += bhi(w.y);
        a4 += blo(w.z); a5 += bhi(w.z); a6 += blo(w.w); a7 += bhi(w.w);
        b0 += blo(z.x); b1 += bhi(z.x); b2 += blo(z.y); b3 += bhi(z.y);
        b4 += blo(z.z); b5 += bhi(z.z); b6 += blo(z.w); b7 += bhi(z.w);
    }
    for (; j < end; j++) {
        int s0 = adj[j];
        uint4 u = xb4[(size_t)s0 * 12 + c];
        a0 += blo(u.x); a1 += bhi(u.x); a2 += blo(u.y); a3 += bhi(u.y);
        a4 += blo(u.z); a5 += bhi(u.z); a6 += blo(u.w); a7 += bhi(u.w);
    }
    a0 += b0; a1 += b1; a2 += b2; a3 += b3;
    a4 += b4; a5 += b5; a6 += b6; a7 += b7;
    float id = 1.0f / (float)max(d, 1);
    uint4 w;
    w.x = pack2(a0 * id, a1 * id); w.y = pack2(a2 * id, a3 * id);
    w.z = pack2(a4 * id, a5 * id); w.w = pack2(a6 * id, a7 * id);
    agg4[(size_t)node * 12 + c] = w;
}

// ---------------------------------------------------------------------------
// Fused GEMM1+GEMM2 (bf16 MFMA), 64-row tiles. R7: weights are loaded
// global->registers per lane (L2-hot 81KB, statically-known fragments) --
// no weight LDS staging. LDS = la only (25.6KB) -> ~4 blocks/CU (was 2).
//   h  = relu([agg|x] @ W1t^T + b1)  in LDS; [p|q] = h @ W2t^T.
// ---------------------------------------------------------------------------
__global__ __launch_bounds__(256) void gemm12_fused(
    const uint4* __restrict__ agg4, const uint4* __restrict__ xb4,
    const uint4* __restrict__ w1t4, const uint4* __restrict__ w2t4,
    const float* __restrict__ b1, const float* __restrict__ b2,
    unsigned short* __restrict__ p, float* __restrict__ out)
{
    constexpr int KP = 200;   // stage-1 A stride in shorts (192+8 pad)
    constexpr int KQ = 136;   // stage-2 A stride in shorts (128+8 pad)
    __shared__ unsigned short la[64 * KP];    // 25600 B (reused for h-tile)
    int t = threadIdx.x;
    uint4* la4 = (uint4*)la;

    int wave = t >> 6, lane = t & 63;
    int m = lane & 15, half = lane >> 4;          // half: 0..3
    int koff = half * 8;

    // B1 fragments from global (issued first; overlap A-staging latency).
    // W1t is [128][192] bf16 = [128][24] short8; frag = col*24 + kk*4 + half.
    const short8* w1s = (const short8*)w1t4;
    short8 B1r[6][2];
#pragma unroll
    for (int kk = 0; kk < 6; kk++) {
        B1r[kk][0] = w1s[(wave * 32 + m)      * 24 + kk * 4 + half];
        B1r[kk][1] = w1s[(wave * 32 + 16 + m) * 24 + kk * 4 + half];
    }

    // stage A [64][192]: k 0..95 from agg, 96..191 from xb
    int row0 = blockIdx.x * 64;
    for (int i = t; i < 64 * 24; i += 256) {
        int r = i / 24, c = i - r * 24;
        // rows >= N_NODES read pad rows (valid mem, rows discarded)
        la4[r * 25 + c] = (c < 12)
            ? agg4[(size_t)(row0 + r) * 12 + c]
            : xb4[(size_t)(row0 + r) * 12 + (c - 12)];
    }
    __syncthreads();

    f32x4 acc[4][2] = {};
#pragma unroll
    for (int kk = 0; kk < 6; kk++) {
        int k0 = kk * 32;
#pragma unroll
        for (int g = 0; g < 4; g++) {
            short8 A = *(const short8*)&la[(g * 16 + m) * KP + k0 + koff];
            acc[g][0] = __builtin_amdgcn_mfma_f32_16x16x32_bf16(A, B1r[kk][0], acc[g][0], 0, 0, 0);
            acc[g][1] = __builtin_amdgcn_mfma_f32_16x16x32_bf16(A, B1r[kk][1], acc[g][1], 0, 0, 0);
        }
    }
    __syncthreads();   // all waves done reading la before h overwrite

    // B2 fragments from global (issued before h-write to hide L2 latency).
    // W2t is [128][128] bf16 = [128][16] short8.
    const short8* w2s = (const short8*)w2t4;
    short8 B2r[4][2];
#pragma unroll
    for (int kk = 0; kk < 4; kk++) {
        B2r[kk][0] = w2s[(wave * 32 + m)      * 16 + kk * 4 + half];
        B2r[kk][1] = w2s[(wave * 32 + 16 + m) * 16 + kk * 4 + half];
    }

    // h-tile (bias+relu, bf16) -> la with stride KQ
    int col0 = wave * 32 + m, col1 = col0 + 16;
    {
        float bias0 = b1[col0], bias1 = b1[col1];
#pragma unroll
        for (int g = 0; g < 4; g++) {
#pragma unroll
            for (int reg = 0; reg < 4; reg++) {
                int hr = g * 16 + half * 4 + reg;
                la[hr * KQ + col0] = (unsigned short)f2bf(fmaxf(acc[g][0][reg] + bias0, 0.f));
                la[hr * KQ + col1] = (unsigned short)f2bf(fmaxf(acc[g][1][reg] + bias1, 0.f));
            }
        }
    }
    __syncthreads();

    f32x4 acc2[4][2] = {};
#pragma unroll
    for (int kk = 0; kk < 4; kk++) {
        int k0 = kk * 32;
#pragma unroll
        for (int g = 0; g < 4; g++) {
            short8 A = *(const short8*)&la[(g * 16 + m) * KQ + k0 + koff];
            acc2[g][0] = __builtin_amdgcn_mfma_f32_16x16x32_bf16(A, B2r[kk][0], acc2[g][0], 0, 0, 0);
            acc2[g][1] = __builtin_amdgcn_mfma_f32_16x16x32_bf16(A, B2r[kk][1], acc2[g][1], 0, 0, 0);
        }
    }
#pragma unroll
    for (int g = 0; g < 4; g++) {
#pragma unroll
        for (int reg = 0; reg < 4; reg++) {
            int r = row0 + g * 16 + half * 4 + reg;
            if (r >= N_NODES) continue;
            float v0 = acc2[g][0][reg], v1 = acc2[g][1][reg];
            if (col0 < 64) p[(size_t)r * 64 + col0] = (unsigned short)f2bf(v0);
            else           out[(size_t)r * 64 + col0 - 64] = v0 + b2[col0 - 64];
            if (col1 < 64) p[(size_t)r * 64 + col1] = (unsigned short)f2bf(v1);
            else           out[(size_t)r * 64 + col1 - 64] = v1 + b2[col1 - 64];
        }
    }
}

// ---------------------------------------------------------------------------
// Gather 2 + finalize: out[n] += (sum_{j in N(n)} p[j]) / deg(n)
// thread = (node, 16B chunk c in 0..7); 4-edge unroll (R4-proven).
// ---------------------------------------------------------------------------
__global__ __launch_bounds__(256) void gather2_kernel(
    const int* __restrict__ rowstart, const int* __restrict__ cnt,
    const int* __restrict__ adj, const uint4* __restrict__ p4,
    float* __restrict__ out)
{
    int idx = blockIdx.x * 256 + threadIdx.x;
    if (idx >= N_NODES * 8) return;
    int node = idx >> 3;
    int c = idx & 7;
    int beg = rowstart[node];
    int d = cnt[node];
    int end = beg + d;
    float a0=0,a1=0,a2=0,a3=0,a4=0,a5=0,a6=0,a7=0;
    float b0=0,b1=0,b2=0,b3=0,b4=0,b5=0,b6=0,b7=0;
    int j = beg;
    for (; j + 3 < end; j += 4) {
        int s0 = adj[j];
        int s1 = adj[j + 1];
        int s2 = adj[j + 2];
        int s3 = adj[j + 3];
        uint4 u = p4[(size_t)s0 * 8 + c];
        uint4 v = p4[(size_t)s1 * 8 + c];
        uint4 w = p4[(size_t)s2 * 8 + c];
        uint4 z = p4[(size_t)s3 * 8 + c];
        a0 += blo(u.x); a1 += bhi(u.x); a2 += blo(u.y); a3 += bhi(u.y);
        a4 += blo(u.z); a5 += bhi(u.z); a6 += blo(u.w); a7 += bhi(u.w);
        b0 += blo(v.x); b1 += bhi(v.x); b2 += blo(v.y); b3 += bhi(v.y);
        b4 += blo(v.z); b5 += bhi(v.z); b6 += blo(v.w); b7 += bhi(v.w);
        a0 += blo(w.x); a1 += bhi(w.x); a2 += blo(w.y); a3 += bhi(w.y);
        a4 += blo(w.z); a5 += bhi(w.z); a6 += blo(w.w); a7 += bhi(w.w);
        b0 += blo(z.x); b1 += bhi(z.x); b2 += blo(z.y); b3 += bhi(z.y);
        b4 += blo(z.z); b5 += bhi(z.z); b6 += blo(z.w); b7 += bhi(z.w);
    }
    for (; j < end; j++) {
        int s0 = adj[j];
        uint4 u = p4[(size_t)s0 * 8 + c];
        a0 += blo(u.x); a1 += bhi(u.x); a2 += blo(u.y); a3 += bhi(u.y);
        a4 += blo(u.z); a5 += bhi(u.z); a6 += blo(u.w); a7 += bhi(u.w);
    }
    a0 += b0; a1 += b1; a2 += b2; a3 += b3;
    a4 += b4; a5 += b5; a6 += b6; a7 += b7;
    float id = 1.0f / (float)max(d, 1);
    float4* o4 = (float4*)out;
    size_t base = (size_t)node * 16 + 2 * c;
    float4 u = o4[base], v = o4[base + 1];
    u.x = fmaf(a0, id, u.x); u.y = fmaf(a1, id, u.y);
    u.z = fmaf(a2, id, u.z); u.w = fmaf(a3, id, u.w);
    v.x = fmaf(a4, id, v.x); v.y = fmaf(a5, id, v.y);
    v.z = fmaf(a6, id, v.z); v.w = fmaf(a7, id, v.w);
    o4[base] = u; o4[base + 1] = v;
}

extern "C" void kernel_launch(void* const* d_in, const int* in_sizes, int n_in,
                              void* d_out, int out_size, void* d_ws, size_t ws_size,
                              hipStream_t stream)
{
    const float* x   = (const float*)d_in[0];
    const int*   ei  = (const int*)d_in[1];
    const float* w1l = (const float*)d_in[2];
    const float* w1r = (const float*)d_in[3];
    const float* b1  = (const float*)d_in[4];
    const float* w2l = (const float*)d_in[5];
    const float* w2r = (const float*)d_in[6];
    const float* b2  = (const float*)d_in[7];
    float* out = (float*)d_out;

    int E = in_sizes[1] / 2;                  // edge_index is [2, E]
    const int* src = ei;
    const int* dst = ei + E;

    // Workspace layout (4B units, arrays kept 16B-aligned).
    int* gcnt     = (int*)d_ws;                        // 256 (200 used)
    int* cnt      = gcnt + 256;                        // 50000
    int* rowstart = cnt + N_NODES;                     // 50000
    unsigned int* pairs = (unsigned int*)(rowstart + N_NODES); // NB*BCAP
    int* adj      = (int*)(pairs + NB * BCAP);         // NB*BCAP
    unsigned short* xb  = (unsigned short*)(adj + NB * BCAP); // MROWS*96 bf16
    unsigned short* agg = xb + (size_t)MROWS * IN_C;   // MROWS*96 bf16
    unsigned short* p   = agg + (size_t)MROWS * IN_C;  // 50000*64 bf16
    unsigned short* Wt1 = p  + (size_t)N_NODES * 64;   // 128*192 bf16
    unsigned short* Wt2 = Wt1 + 128 * 192;             // 128*128 bf16

    // conv first (also zeroes gcnt; stream order covers the dependency)
    conv_all_kernel<<<XBLKS + WBLKS, 256, 0, stream>>>(
        x, (uint4*)xb, w1l, w1r, w2l, w2r, Wt1, Wt2, gcnt);

    // CSR build: 2 kernels (single-pass bucket scatter + per-bucket CSR)
    csr_scatter<<<NWG, 256, 0, stream>>>(src, dst, gcnt, pairs, E);
    partb_csr<<<NB, 256, 0, stream>>>(pairs, gcnt, rowstart, cnt, adj);

    gather1_kernel<<<(N_NODES * 12 + 255) / 256, 256, 0, stream>>>(
        rowstart, cnt, adj, (const uint4*)xb, (uint4*)agg);

    gemm12_fused<<<MROWS / 64, 256, 0, stream>>>(
        (const uint4*)agg, (const uint4*)xb, (const uint4*)Wt1, (const uint4*)Wt2,
        b1, b2, p, out);

    gather2_kernel<<<(N_NODES * 8 + 255) / 256, 256, 0, stream>>>(
        rowstart, cnt, adj, (const uint4*)p, out);
}